// Round 1
// baseline (887.614 us; speedup 1.0000x reference)
//
#include <hip/hip_runtime.h>
#include <hip/hip_bf16.h>
#include <math.h>

#define B_TOK 8192
#define DDIM  1024
#define HDIM  4096
#define NEXP  8
#define CAP   17408   // 16384 routed pairs + 8*127 padding, rounded up

typedef unsigned short u16;
using f32x4  = __attribute__((ext_vector_type(4))) float;
using bf16x8 = __attribute__((ext_vector_type(8))) short;  // 8 bf16 in 4 VGPRs

__device__ __forceinline__ u16 f2bf(float f) {
  union { float f; unsigned u; } v; v.f = f;
  unsigned r = v.u + 0x7FFFu + ((v.u >> 16) & 1u);  // RNE
  return (u16)(r >> 16);
}

__device__ __forceinline__ void load_lds16(const void* g, void* l) {
  __builtin_amdgcn_global_load_lds((const __attribute__((address_space(1))) void*)g,
                                   (__attribute__((address_space(3))) void*)l,
                                   16, 0, 0);
}

// ---------------- f32 -> bf16 conversion (vectorized) ----------------
__global__ __launch_bounds__(256) void cvt_kernel(const float4* __restrict__ src,
                                                  ushort4* __restrict__ dst, int n4) {
  for (int i = blockIdx.x * 256 + threadIdx.x; i < n4; i += gridDim.x * 256) {
    float4 v = src[i];
    ushort4 o;
    o.x = f2bf(v.x); o.y = f2bf(v.y); o.z = f2bf(v.z); o.w = f2bf(v.w);
    dst[i] = o;
  }
}

// ---------------- gating: logits (f64 accum), top-2, softmax ----------------
__global__ __launch_bounds__(256) void gate_kernel(
    const float* __restrict__ inp, const float* __restrict__ gw,
    const float* __restrict__ gb, int* __restrict__ tok_e,
    float* __restrict__ tok_g, int* __restrict__ counts)
{
  int gtid = blockIdx.x * 256 + threadIdx.x;
  int tok  = gtid >> 6;
  int lane = threadIdx.x & 63;
  if (tok >= B_TOK) return;
  const float4* X = (const float4*)(inp + (size_t)tok * DDIM);
  float4 x[4];
#pragma unroll
  for (int j = 0; j < 4; ++j) x[j] = X[j * 64 + lane];
  float lg[NEXP];
#pragma unroll
  for (int e = 0; e < NEXP; ++e) {
    const float4* W = (const float4*)(gw + e * DDIM);
    double s = 0.0;
#pragma unroll
    for (int j = 0; j < 4; ++j) {
      float4 w = W[j * 64 + lane];
      s += (double)x[j].x * w.x + (double)x[j].y * w.y
         + (double)x[j].z * w.z + (double)x[j].w * w.w;
    }
#pragma unroll
    for (int o = 32; o > 0; o >>= 1) s += __shfl_xor(s, o);
    lg[e] = (float)(s + (double)gb[e]);
  }
  if (lane == 0) {
    int i0 = 0; float v0 = lg[0];
#pragma unroll
    for (int e = 1; e < NEXP; ++e) if (lg[e] > v0) { v0 = lg[e]; i0 = e; }
    int i1 = -1; float v1 = -3.4e38f;
#pragma unroll
    for (int e = 0; e < NEXP; ++e) if (e != i0 && lg[e] > v1) { v1 = lg[e]; i1 = e; }
    float t   = __expf(v1 - v0);
    float inv = 1.0f / (1.0f + t);
    tok_e[2 * tok] = i0; tok_e[2 * tok + 1] = i1;
    tok_g[2 * tok] = inv; tok_g[2 * tok + 1] = t * inv;
    atomicAdd(&counts[i0], 1);
    atomicAdd(&counts[i1], 1);
  }
}

// ---------------- offsets (pad each expert to 128) ----------------
__global__ void scan_kernel(const int* __restrict__ counts, int* __restrict__ offs,
                            int* __restrict__ padded)
{
  if (threadIdx.x == 0 && blockIdx.x == 0) {
    int off = 0;
    for (int e = 0; e < NEXP; ++e) {
      offs[e] = off;
      int p = (counts[e] + 127) & ~127;
      padded[e] = p;
      off += p;
    }
  }
}

// ---------------- scatter tokens into expert slots ----------------
__global__ __launch_bounds__(256) void scatter_kernel(
    const int* __restrict__ tok_e, const float* __restrict__ tok_g,
    const int* __restrict__ offs, int* __restrict__ cursors,
    int* __restrict__ slot_token, float* __restrict__ slot_gate)
{
  int b = blockIdx.x * 256 + threadIdx.x;
  if (b >= B_TOK) return;
#pragma unroll
  for (int k = 0; k < 2; ++k) {
    int e   = tok_e[2 * b + k];
    float g = tok_g[2 * b + k];
    int pos = atomicAdd(&cursors[e], 1);
    int s   = offs[e] + pos;
    slot_token[s] = b;
    slot_gate[s]  = g;
  }
}

// ---------------- GEMM1: h = relu(X_gather @ W1[e]^T + b1[e]) -> bf16 ----------------
__global__ __launch_bounds__(256) void gemm1_kernel(
    const u16* __restrict__ Xb, const u16* __restrict__ W1b,
    const float* __restrict__ b1, const int* __restrict__ slot_token,
    const int* __restrict__ offs, const int* __restrict__ padded,
    u16* __restrict__ Hb)
{
  const int e = blockIdx.z;
  if ((int)(blockIdx.y * 128) >= padded[e]) return;
  const int base_slot = offs[e] + blockIdx.y * 128;
  const int n0 = blockIdx.x * 128;

  __shared__ __align__(16) u16 As[128 * 32];
  __shared__ __align__(16) u16 Bs[128 * 32];
  __shared__ int toks[128];

  const int tid = threadIdx.x;
  if (tid < 128) toks[tid] = slot_token[base_slot + tid];
  __syncthreads();

  const u16* a_src[2];
  const u16* b_src[2];
  int lds_off[2];
#pragma unroll
  for (int i = 0; i < 2; ++i) {
    int idx = i * 256 + tid;
    int row = idx >> 2, seg = idx & 3;
    a_src[i] = Xb + (size_t)toks[row] * DDIM + seg * 8;
    b_src[i] = W1b + ((size_t)e * HDIM + (size_t)(n0 + row)) * DDIM + seg * 8;
    lds_off[i] = idx * 8;
  }

  f32x4 acc[4][4];
#pragma unroll
  for (int m = 0; m < 4; ++m)
#pragma unroll
    for (int n = 0; n < 4; ++n) acc[m][n] = f32x4{0.f, 0.f, 0.f, 0.f};

  const int wave = tid >> 6, lane = tid & 63;
  const int wm = (wave >> 1) * 64, wn = (wave & 1) * 64;
  const int fr = lane & 15, fq = lane >> 4;

  for (int k0 = 0; k0 < DDIM; k0 += 32) {
    __syncthreads();
#pragma unroll
    for (int i = 0; i < 2; ++i) {
      load_lds16(a_src[i] + k0, &As[lds_off[i]]);
      load_lds16(b_src[i] + k0, &Bs[lds_off[i]]);
    }
    __syncthreads();
    bf16x8 af[4], bfr[4];
#pragma unroll
    for (int m = 0; m < 4; ++m)
      af[m] = *(const bf16x8*)&As[(wm + m * 16 + fr) * 32 + fq * 8];
#pragma unroll
    for (int n = 0; n < 4; ++n)
      bfr[n] = *(const bf16x8*)&Bs[(wn + n * 16 + fr) * 32 + fq * 8];
#pragma unroll
    for (int m = 0; m < 4; ++m)
#pragma unroll
      for (int n = 0; n < 4; ++n)
        acc[m][n] = __builtin_amdgcn_mfma_f32_16x16x32_bf16(af[m], bfr[n], acc[m][n], 0, 0, 0);
  }

#pragma unroll
  for (int n = 0; n < 4; ++n) {
    int col = n0 + wn + n * 16 + fr;
    float bias = b1[e * HDIM + col];
#pragma unroll
    for (int m = 0; m < 4; ++m) {
      int row0 = wm + m * 16 + fq * 4;
#pragma unroll
      for (int j = 0; j < 4; ++j) {
        float v = acc[m][n][j] + bias;
        v = v > 0.f ? v : 0.f;
        Hb[(size_t)(base_slot + row0 + j) * HDIM + col] = f2bf(v);
      }
    }
  }
}

// ---------------- GEMM2: p = gate*exp(relu(H @ W2[e]^T + b2[e])), atomic add ----------------
__global__ __launch_bounds__(256) void gemm2_kernel(
    const u16* __restrict__ Hb, const u16* __restrict__ W2b,
    const float* __restrict__ b2, const float* __restrict__ slot_gate,
    const int* __restrict__ slot_token, const int* __restrict__ offs,
    const int* __restrict__ padded, float* __restrict__ out)
{
  const int e = blockIdx.z;
  if ((int)(blockIdx.y * 128) >= padded[e]) return;
  const int base_slot = offs[e] + blockIdx.y * 128;
  const int n0 = blockIdx.x * 128;

  __shared__ __align__(16) u16 As[128 * 32];
  __shared__ __align__(16) u16 Bs[128 * 32];
  __shared__ int   toks[128];
  __shared__ float gts[128];

  const int tid = threadIdx.x;
  if (tid < 128) {
    toks[tid] = slot_token[base_slot + tid];
    gts[tid]  = slot_gate[base_slot + tid];
  }

  const u16* a_src[2];
  const u16* b_src[2];
  int lds_off[2];
#pragma unroll
  for (int i = 0; i < 2; ++i) {
    int idx = i * 256 + tid;
    int row = idx >> 2, seg = idx & 3;
    a_src[i] = Hb + (size_t)(base_slot + row) * HDIM + seg * 8;
    b_src[i] = W2b + ((size_t)e * DDIM + (size_t)(n0 + row)) * HDIM + seg * 8;
    lds_off[i] = idx * 8;
  }

  f32x4 acc[4][4];
#pragma unroll
  for (int m = 0; m < 4; ++m)
#pragma unroll
    for (int n = 0; n < 4; ++n) acc[m][n] = f32x4{0.f, 0.f, 0.f, 0.f};

  const int wave = tid >> 6, lane = tid & 63;
  const int wm = (wave >> 1) * 64, wn = (wave & 1) * 64;
  const int fr = lane & 15, fq = lane >> 4;

  for (int k0 = 0; k0 < HDIM; k0 += 32) {
    __syncthreads();
#pragma unroll
    for (int i = 0; i < 2; ++i) {
      load_lds16(a_src[i] + k0, &As[lds_off[i]]);
      load_lds16(b_src[i] + k0, &Bs[lds_off[i]]);
    }
    __syncthreads();
    bf16x8 af[4], bfr[4];
#pragma unroll
    for (int m = 0; m < 4; ++m)
      af[m] = *(const bf16x8*)&As[(wm + m * 16 + fr) * 32 + fq * 8];
#pragma unroll
    for (int n = 0; n < 4; ++n)
      bfr[n] = *(const bf16x8*)&Bs[(wn + n * 16 + fr) * 32 + fq * 8];
#pragma unroll
    for (int m = 0; m < 4; ++m)
#pragma unroll
      for (int n = 0; n < 4; ++n)
        acc[m][n] = __builtin_amdgcn_mfma_f32_16x16x32_bf16(af[m], bfr[n], acc[m][n], 0, 0, 0);
  }

#pragma unroll
  for (int n = 0; n < 4; ++n) {
    int col = n0 + wn + n * 16 + fr;
    float bias = b2[e * DDIM + col];
#pragma unroll
    for (int m = 0; m < 4; ++m) {
      int row0 = wm + m * 16 + fq * 4;
#pragma unroll
      for (int j = 0; j < 4; ++j) {
        int row = row0 + j;
        float v = acc[m][n][j] + bias;
        v = v > 0.f ? v : 0.f;
        float p = gts[row] * __expf(v);
        atomicAdd(&out[(size_t)toks[row] * DDIM + col], p);
      }
    }
  }
}

// ---------------- final: out = log(out + eps), in place ----------------
__global__ __launch_bounds__(256) void log_kernel(float4* __restrict__ out, int n4) {
  const float EPS = 2.220446049250313e-16f;
  for (int i = blockIdx.x * 256 + threadIdx.x; i < n4; i += gridDim.x * 256) {
    float4 v = out[i];
    v.x = logf(v.x + EPS);
    v.y = logf(v.y + EPS);
    v.z = logf(v.z + EPS);
    v.w = logf(v.w + EPS);
    out[i] = v;
  }
}

extern "C" void kernel_launch(void* const* d_in, const int* in_sizes, int n_in,
                              void* d_out, int out_size, void* d_ws, size_t ws_size,
                              hipStream_t stream)
{
  const float* inp = (const float*)d_in[0];
  const float* gw  = (const float*)d_in[1];
  const float* gb  = (const float*)d_in[2];
  const float* W1  = (const float*)d_in[3];
  const float* b1  = (const float*)d_in[4];
  const float* W2  = (const float*)d_in[5];
  const float* b2  = (const float*)d_in[6];
  float* out = (float*)d_out;

  char* ws = (char*)d_ws;
  size_t off = 0;
  auto alloc = [&](size_t bytes) {
    void* p = ws + off;
    off = (off + bytes + 255) & ~(size_t)255;
    return p;
  };
  u16*   Xb  = (u16*)alloc((size_t)B_TOK * DDIM * 2);
  u16*   W1b = (u16*)alloc((size_t)NEXP * HDIM * DDIM * 2);
  u16*   W2b = (u16*)alloc((size_t)NEXP * DDIM * HDIM * 2);
  u16*   Hb  = (u16*)alloc((size_t)CAP * HDIM * 2);
  int*   slot_token = (int*)alloc(CAP * 4);
  float* slot_gate  = (float*)alloc(CAP * 4);
  int*   tok_e = (int*)alloc(B_TOK * 2 * 4);
  float* tok_g = (float*)alloc(B_TOK * 2 * 4);
  int*   counts  = (int*)alloc(32);
  int*   offs    = (int*)alloc(32);
  int*   padded  = (int*)alloc(32);
  int*   cursors = (int*)alloc(32);

  hipMemsetAsync(counts, 0, 32, stream);
  hipMemsetAsync(cursors, 0, 32, stream);
  hipMemsetAsync(slot_token, 0, CAP * 4, stream);
  hipMemsetAsync(slot_gate, 0, CAP * 4, stream);
  hipMemsetAsync(out, 0, (size_t)out_size * 4, stream);

  cvt_kernel<<<2048, 256, 0, stream>>>((const float4*)inp, (ushort4*)Xb, B_TOK * DDIM / 4);
  cvt_kernel<<<2048, 256, 0, stream>>>((const float4*)W1, (ushort4*)W1b, NEXP * HDIM * DDIM / 4);
  cvt_kernel<<<2048, 256, 0, stream>>>((const float4*)W2, (ushort4*)W2b, NEXP * DDIM * HDIM / 4);

  gate_kernel<<<B_TOK / 4, 256, 0, stream>>>(inp, gw, gb, tok_e, tok_g, counts);
  scan_kernel<<<1, 64, 0, stream>>>(counts, offs, padded);
  scatter_kernel<<<B_TOK / 256, 256, 0, stream>>>(tok_e, tok_g, offs, cursors,
                                                  slot_token, slot_gate);

  gemm1_kernel<<<dim3(HDIM / 128, 64, NEXP), 256, 0, stream>>>(
      Xb, W1b, b1, slot_token, offs, padded, Hb);
  gemm2_kernel<<<dim3(DDIM / 128, 64, NEXP), 256, 0, stream>>>(
      Hb, W2b, b2, slot_gate, slot_token, offs, padded, out);

  log_kernel<<<2048, 256, 0, stream>>>((float4*)out, out_size / 4);
}

// Round 3
// 876.057 us; speedup vs baseline: 1.0132x; 1.0132x over previous
//
#include <hip/hip_runtime.h>
#include <hip/hip_bf16.h>
#include <math.h>

#define B_TOK 8192
#define DDIM  1024
#define HDIM  4096
#define NEXP  8
#define CAP   17408   // 16384 routed pairs + 8*127 padding, rounded up
#define TILE_ELEMS (128 * 32)

typedef unsigned short u16;
using f32x4  = __attribute__((ext_vector_type(4))) float;
using bf16x8 = __attribute__((ext_vector_type(8))) short;  // 8 bf16 in 4 VGPRs

__device__ __forceinline__ u16 f2bf(float f) {
  union { float f; unsigned u; } v; v.f = f;
  unsigned r = v.u + 0x7FFFu + ((v.u >> 16) & 1u);  // RNE
  return (u16)(r >> 16);
}

__device__ __forceinline__ void load_lds16(const void* g, void* l) {
  __builtin_amdgcn_global_load_lds((const __attribute__((address_space(1))) void*)g,
                                   (__attribute__((address_space(3))) void*)l,
                                   16, 0, 0);
}

// ---------------- f32 -> bf16 conversion (vectorized) ----------------
__global__ __launch_bounds__(256) void cvt_kernel(const float4* __restrict__ src,
                                                  ushort4* __restrict__ dst, int n4) {
  for (int i = blockIdx.x * 256 + threadIdx.x; i < n4; i += gridDim.x * 256) {
    float4 v = src[i];
    ushort4 o;
    o.x = f2bf(v.x); o.y = f2bf(v.y); o.z = f2bf(v.z); o.w = f2bf(v.w);
    dst[i] = o;
  }
}

// ---------------- gating: logits (f64 accum), top-2, softmax ----------------
__global__ __launch_bounds__(256) void gate_kernel(
    const float* __restrict__ inp, const float* __restrict__ gw,
    const float* __restrict__ gb, int* __restrict__ tok_e,
    float* __restrict__ tok_g, int* __restrict__ counts)
{
  int gtid = blockIdx.x * 256 + threadIdx.x;
  int tok  = gtid >> 6;
  int lane = threadIdx.x & 63;
  if (tok >= B_TOK) return;
  const float4* X = (const float4*)(inp + (size_t)tok * DDIM);
  float4 x[4];
#pragma unroll
  for (int j = 0; j < 4; ++j) x[j] = X[j * 64 + lane];
  float lg[NEXP];
#pragma unroll
  for (int e = 0; e < NEXP; ++e) {
    const float4* W = (const float4*)(gw + e * DDIM);
    double s = 0.0;
#pragma unroll
    for (int j = 0; j < 4; ++j) {
      float4 w = W[j * 64 + lane];
      s += (double)x[j].x * w.x + (double)x[j].y * w.y
         + (double)x[j].z * w.z + (double)x[j].w * w.w;
    }
#pragma unroll
    for (int o = 32; o > 0; o >>= 1) s += __shfl_xor(s, o);
    lg[e] = (float)(s + (double)gb[e]);
  }
  if (lane == 0) {
    int i0 = 0; float v0 = lg[0];
#pragma unroll
    for (int e = 1; e < NEXP; ++e) if (lg[e] > v0) { v0 = lg[e]; i0 = e; }
    int i1 = -1; float v1 = -3.4e38f;
#pragma unroll
    for (int e = 0; e < NEXP; ++e) if (e != i0 && lg[e] > v1) { v1 = lg[e]; i1 = e; }
    float t   = __expf(v1 - v0);
    float inv = 1.0f / (1.0f + t);
    tok_e[2 * tok] = i0; tok_e[2 * tok + 1] = i1;
    tok_g[2 * tok] = inv; tok_g[2 * tok + 1] = t * inv;
    atomicAdd(&counts[i0], 1);
    atomicAdd(&counts[i1], 1);
  }
}

// ---------------- offsets (pad each expert to 128) ----------------
__global__ void scan_kernel(const int* __restrict__ counts, int* __restrict__ offs,
                            int* __restrict__ padded)
{
  if (threadIdx.x == 0 && blockIdx.x == 0) {
    int off = 0;
    for (int e = 0; e < NEXP; ++e) {
      offs[e] = off;
      int p = (counts[e] + 127) & ~127;
      padded[e] = p;
      off += p;
    }
  }
}

// ---------------- scatter tokens into expert slots ----------------
__global__ __launch_bounds__(256) void scatter_kernel(
    const int* __restrict__ tok_e, const float* __restrict__ tok_g,
    const int* __restrict__ offs, int* __restrict__ cursors,
    int* __restrict__ slot_token, float* __restrict__ slot_gate)
{
  int b = blockIdx.x * 256 + threadIdx.x;
  if (b >= B_TOK) return;
#pragma unroll
  for (int k = 0; k < 2; ++k) {
    int e   = tok_e[2 * b + k];
    float g = tok_g[2 * b + k];
    int pos = atomicAdd(&cursors[e], 1);
    int s   = offs[e] + pos;
    slot_token[s] = b;
    slot_gate[s]  = g;
  }
}

// Pipeline helpers --------------------------------------------------
#define PIPE_STAGE(slot, kt)                                            \
  do {                                                                  \
    const int _k = (kt) * 32;                                           \
    load_lds16(pa0 + _k, &As[(slot)][lo0]);                             \
    load_lds16(pa1 + _k, &As[(slot)][lo1]);                             \
    load_lds16(pb0 + _k, &Bs[(slot)][lo0]);                             \
    load_lds16(pb1 + _k, &Bs[(slot)][lo1]);                             \
  } while (0)

#define WAITCNT4 asm volatile("s_waitcnt vmcnt(4)" ::: "memory")
#define WAITCNT0 asm volatile("s_waitcnt vmcnt(0)" ::: "memory")
#define BARRIER_PIN                                                     \
  do { __builtin_amdgcn_s_barrier();                                    \
       __builtin_amdgcn_sched_barrier(0); } while (0)

// ---------------- GEMM1: h = relu(X_gather @ W1[e]^T + b1[e]) -> bf16 ----------------
__global__ __launch_bounds__(256) void gemm1_kernel(
    const u16* __restrict__ Xb, const u16* __restrict__ W1b,
    const float* __restrict__ b1, const int* __restrict__ slot_token,
    const int* __restrict__ offs, const int* __restrict__ padded,
    u16* __restrict__ Hb)
{
  const int e = blockIdx.z;
  if ((int)(blockIdx.y * 128) >= padded[e]) return;
  const int base_slot = offs[e] + blockIdx.y * 128;
  const int n0 = blockIdx.x * 128;
  const int NT = DDIM / 32;  // 32

  __shared__ __align__(16) u16 As[3][TILE_ELEMS];
  __shared__ __align__(16) u16 Bs[3][TILE_ELEMS];
  __shared__ int toks[128];

  const int tid = threadIdx.x;
  if (tid < 128) toks[tid] = slot_token[base_slot + tid];
  __syncthreads();  // toks visible; also drains the tid<128 global loads

  const int idx0 = tid, idx1 = 256 + tid;
  const u16* pa0 = Xb + (size_t)toks[idx0 >> 2] * DDIM + (idx0 & 3) * 8;
  const u16* pa1 = Xb + (size_t)toks[idx1 >> 2] * DDIM + (idx1 & 3) * 8;
  const u16* pb0 = W1b + ((size_t)e * HDIM + (size_t)(n0 + (idx0 >> 2))) * DDIM + (idx0 & 3) * 8;
  const u16* pb1 = W1b + ((size_t)e * HDIM + (size_t)(n0 + (idx1 >> 2))) * DDIM + (idx1 & 3) * 8;
  const int lo0 = idx0 * 8, lo1 = idx1 * 8;

  f32x4 acc[4][4];
#pragma unroll
  for (int m = 0; m < 4; ++m)
#pragma unroll
    for (int n = 0; n < 4; ++n) acc[m][n] = f32x4{0.f, 0.f, 0.f, 0.f};

  const int wave = tid >> 6, lane = tid & 63;
  const int wm = (wave >> 1) * 64, wn = (wave & 1) * 64;
  const int fr = lane & 15, fq = lane >> 4;

  // prologue: stages for tiles 0 and 1
  PIPE_STAGE(0, 0);
  PIPE_STAGE(1, 1);
  WAITCNT4;      // tile 0 landed (tile 1 still in flight)
  BARRIER_PIN;

  int cur = 0;
  for (int t = 0; t < NT; ++t) {
    int stg = cur + 2; if (stg >= 3) stg -= 3;
    if (t + 2 < NT) PIPE_STAGE(stg, t + 2);

    const u16* Ac = &As[cur][0];
    const u16* Bc = &Bs[cur][0];
    bf16x8 af[4], bfr[4];
#pragma unroll
    for (int m = 0; m < 4; ++m)
      af[m] = *(const bf16x8*)&Ac[(wm + m * 16 + fr) * 32 + fq * 8];
#pragma unroll
    for (int n = 0; n < 4; ++n)
      bfr[n] = *(const bf16x8*)&Bc[(wn + n * 16 + fr) * 32 + fq * 8];

    __builtin_amdgcn_s_setprio(1);
#pragma unroll
    for (int m = 0; m < 4; ++m)
#pragma unroll
      for (int n = 0; n < 4; ++n)
        acc[m][n] = __builtin_amdgcn_mfma_f32_16x16x32_bf16(af[m], bfr[n], acc[m][n], 0, 0, 0);
    __builtin_amdgcn_s_setprio(0);

    if (t + 2 < NT)      { WAITCNT4; }   // tile t+1 landed, t+2 in flight
    else if (t + 1 < NT) { WAITCNT0; }   // drain last outstanding stage
    BARRIER_PIN;
    cur = (cur + 1 == 3) ? 0 : cur + 1;
  }

#pragma unroll
  for (int n = 0; n < 4; ++n) {
    int col = n0 + wn + n * 16 + fr;
    float bias = b1[e * HDIM + col];
#pragma unroll
    for (int m = 0; m < 4; ++m) {
      int row0 = wm + m * 16 + fq * 4;
#pragma unroll
      for (int j = 0; j < 4; ++j) {
        float v = acc[m][n][j] + bias;
        v = v > 0.f ? v : 0.f;
        Hb[(size_t)(base_slot + row0 + j) * HDIM + col] = f2bf(v);
      }
    }
  }
}

// ---------------- GEMM2: p = gate*exp(relu(H @ W2[e]^T + b2[e])), atomic add ----------------
__global__ __launch_bounds__(256) void gemm2_kernel(
    const u16* __restrict__ Hb, const u16* __restrict__ W2b,
    const float* __restrict__ b2, const float* __restrict__ slot_gate,
    const int* __restrict__ slot_token, const int* __restrict__ offs,
    const int* __restrict__ padded, float* __restrict__ out)
{
  const int e = blockIdx.z;
  if ((int)(blockIdx.y * 128) >= padded[e]) return;
  const int base_slot = offs[e] + blockIdx.y * 128;
  const int n0 = blockIdx.x * 128;
  const int NT = HDIM / 32;  // 128

  __shared__ __align__(16) u16 As[3][TILE_ELEMS];
  __shared__ __align__(16) u16 Bs[3][TILE_ELEMS];
  __shared__ int   toks[128];
  __shared__ float gts[128];

  const int tid = threadIdx.x;
  if (tid < 128) {
    toks[tid] = slot_token[base_slot + tid];
    gts[tid]  = slot_gate[base_slot + tid];
  }
  __syncthreads();  // visibility + drain the tid<128 global loads from vmcnt

  const int idx0 = tid, idx1 = 256 + tid;
  const u16* pa0 = Hb + (size_t)(base_slot + (idx0 >> 2)) * HDIM + (idx0 & 3) * 8;
  const u16* pa1 = Hb + (size_t)(base_slot + (idx1 >> 2)) * HDIM + (idx1 & 3) * 8;
  const u16* pb0 = W2b + ((size_t)e * DDIM + (size_t)(n0 + (idx0 >> 2))) * HDIM + (idx0 & 3) * 8;
  const u16* pb1 = W2b + ((size_t)e * DDIM + (size_t)(n0 + (idx1 >> 2))) * HDIM + (idx1 & 3) * 8;
  const int lo0 = idx0 * 8, lo1 = idx1 * 8;

  f32x4 acc[4][4];
#pragma unroll
  for (int m = 0; m < 4; ++m)
#pragma unroll
    for (int n = 0; n < 4; ++n) acc[m][n] = f32x4{0.f, 0.f, 0.f, 0.f};

  const int wave = tid >> 6, lane = tid & 63;
  const int wm = (wave >> 1) * 64, wn = (wave & 1) * 64;
  const int fr = lane & 15, fq = lane >> 4;

  PIPE_STAGE(0, 0);
  PIPE_STAGE(1, 1);
  WAITCNT4;
  BARRIER_PIN;

  int cur = 0;
  for (int t = 0; t < NT; ++t) {
    int stg = cur + 2; if (stg >= 3) stg -= 3;
    if (t + 2 < NT) PIPE_STAGE(stg, t + 2);

    const u16* Ac = &As[cur][0];
    const u16* Bc = &Bs[cur][0];
    bf16x8 af[4], bfr[4];
#pragma unroll
    for (int m = 0; m < 4; ++m)
      af[m] = *(const bf16x8*)&Ac[(wm + m * 16 + fr) * 32 + fq * 8];
#pragma unroll
    for (int n = 0; n < 4; ++n)
      bfr[n] = *(const bf16x8*)&Bc[(wn + n * 16 + fr) * 32 + fq * 8];

    __builtin_amdgcn_s_setprio(1);
#pragma unroll
    for (int m = 0; m < 4; ++m)
#pragma unroll
      for (int n = 0; n < 4; ++n)
        acc[m][n] = __builtin_amdgcn_mfma_f32_16x16x32_bf16(af[m], bfr[n], acc[m][n], 0, 0, 0);
    __builtin_amdgcn_s_setprio(0);

    if (t + 2 < NT)      { WAITCNT4; }
    else if (t + 1 < NT) { WAITCNT0; }
    BARRIER_PIN;
    cur = (cur + 1 == 3) ? 0 : cur + 1;
  }

#pragma unroll
  for (int n = 0; n < 4; ++n) {
    int col = n0 + wn + n * 16 + fr;
    float bias = b2[e * DDIM + col];
#pragma unroll
    for (int m = 0; m < 4; ++m) {
      int row0 = wm + m * 16 + fq * 4;
#pragma unroll
      for (int j = 0; j < 4; ++j) {
        int row = row0 + j;
        float v = acc[m][n][j] + bias;
        v = v > 0.f ? v : 0.f;
        float p = gts[row] * __expf(v);
        atomicAdd(&out[(size_t)toks[row] * DDIM + col], p);
      }
    }
  }
}

// ---------------- final: out = log(out + eps), in place ----------------
__global__ __launch_bounds__(256) void log_kernel(float4* __restrict__ out, int n4) {
  const float EPS = 2.220446049250313e-16f;
  for (int i = blockIdx.x * 256 + threadIdx.x; i < n4; i += gridDim.x * 256) {
    float4 v = out[i];
    v.x = logf(v.x + EPS);
    v.y = logf(v.y + EPS);
    v.z = logf(v.z + EPS);
    v.w = logf(v.w + EPS);
    out[i] = v;
  }
}

extern "C" void kernel_launch(void* const* d_in, const int* in_sizes, int n_in,
                              void* d_out, int out_size, void* d_ws, size_t ws_size,
                              hipStream_t stream)
{
  const float* inp = (const float*)d_in[0];
  const float* gw  = (const float*)d_in[1];
  const float* gb  = (const float*)d_in[2];
  const float* W1  = (const float*)d_in[3];
  const float* b1  = (const float*)d_in[4];
  const float* W2  = (const float*)d_in[5];
  const float* b2  = (const float*)d_in[6];
  float* out = (float*)d_out;

  char* ws = (char*)d_ws;
  size_t off = 0;
  auto alloc = [&](size_t bytes) {
    void* p = ws + off;
    off = (off + bytes + 255) & ~(size_t)255;
    return p;
  };
  u16*   Xb  = (u16*)alloc((size_t)B_TOK * DDIM * 2);
  u16*   W1b = (u16*)alloc((size_t)NEXP * HDIM * DDIM * 2);
  u16*   W2b = (u16*)alloc((size_t)NEXP * DDIM * HDIM * 2);
  u16*   Hb  = (u16*)alloc((size_t)CAP * HDIM * 2);
  int*   slot_token = (int*)alloc(CAP * 4);
  float* slot_gate  = (float*)alloc(CAP * 4);
  int*   tok_e = (int*)alloc(B_TOK * 2 * 4);
  float* tok_g = (float*)alloc(B_TOK * 2 * 4);
  int*   counts  = (int*)alloc(32);
  int*   offs    = (int*)alloc(32);
  int*   padded  = (int*)alloc(32);
  int*   cursors = (int*)alloc(32);

  (void)hipMemsetAsync(counts, 0, 32, stream);
  (void)hipMemsetAsync(cursors, 0, 32, stream);
  (void)hipMemsetAsync(slot_token, 0, CAP * 4, stream);
  (void)hipMemsetAsync(slot_gate, 0, CAP * 4, stream);
  (void)hipMemsetAsync(out, 0, (size_t)out_size * 4, stream);

  cvt_kernel<<<2048, 256, 0, stream>>>((const float4*)inp, (ushort4*)Xb, B_TOK * DDIM / 4);
  cvt_kernel<<<2048, 256, 0, stream>>>((const float4*)W1, (ushort4*)W1b, NEXP * HDIM * DDIM / 4);
  cvt_kernel<<<2048, 256, 0, stream>>>((const float4*)W2, (ushort4*)W2b, NEXP * DDIM * HDIM / 4);

  gate_kernel<<<B_TOK / 4, 256, 0, stream>>>(inp, gw, gb, tok_e, tok_g, counts);
  scan_kernel<<<1, 64, 0, stream>>>(counts, offs, padded);
  scatter_kernel<<<B_TOK / 256, 256, 0, stream>>>(tok_e, tok_g, offs, cursors,
                                                  slot_token, slot_gate);

  gemm1_kernel<<<dim3(HDIM / 128, 64, NEXP), 256, 0, stream>>>(
      Xb, W1b, b1, slot_token, offs, padded, Hb);
  gemm2_kernel<<<dim3(DDIM / 128, 64, NEXP), 256, 0, stream>>>(
      Hb, W2b, b2, slot_gate, slot_token, offs, padded, out);

  log_kernel<<<2048, 256, 0, stream>>>((float4*)out, out_size / 4);
}